// Round 6
// baseline (119.930 us; speedup 1.0000x reference)
//
#include <hip/hip_runtime.h>

#define N_PTS 32768
#define M_PTS 8192      // N / STRIDE
#define C_IN  64
#define C_OUT 128
#define KNN   16
#define GDIM  67        // 3 + C_IN
#define BN_EPS 1e-5f
#define SBLK  64        // blocks for ustats/uout grid-stride
#define MAXC  64        // centers with candidate-buffer fast path

// workspace offsets (bytes)
#define OFF_FPS   0u          // int[M_PTS]
#define OFF_POS   32768u      // int[N_PTS]
#define OFF_META  163840u     // int[8]: [0]=nuniq [1]=cycStart [2]=cycLen
#define OFF_KNN   163904u     // int[M_PTS*KNN]
#define OFF_CAND  688192u     // u64[MAXC*2048]
#define OFF_PART  1736768u    // float[SBLK*256]
#define OFF_SCALE 1802304u    // float[C_OUT]
#define OFF_SHIFT 1802816u    // float[C_OUT]

typedef unsigned int uint32;
typedef unsigned long long uint64;

// multiplicity of unique slot s in the length-M periodic index sequence
__device__ __forceinline__ int slot_count(int s, int nun, int cs, int cl, int M) {
    if (s < cs) return 1;                 // pre-cycle slot: occurs once
    const int E = M - nun;                // extended (periodic) occurrences
    const int base = E / cl, rem = E % cl;
    const int start = (nun - cs) % cl;    // residue of first extended index
    int off = (s - cs) - start; if (off < 0) off += cl;
    return 1 + base + (off < rem ? 1 : 0);
}

__device__ __forceinline__ uint32 dist_key(float d) {
    uint32 u = __float_as_uint(d);
    return (u & 0x80000000u) ? ~u : (u | 0x80000000u);
}

// ---------------- FPS chain (argmax to LAST point), cycle-detected ----------------
// Points register-cached once; each serial step is pure VALU + one reduce.
__global__ void __launch_bounds__(1024) fps_kernel(const float* __restrict__ p,
                                                   int* __restrict__ fps,
                                                   int* __restrict__ pos,
                                                   int* __restrict__ meta,
                                                   float* __restrict__ newp) {
    __shared__ float wv_d[16];
    __shared__ int   wv_i[16];
    __shared__ int s_last, s_done, s_cs;
    const int tid  = threadIdx.x;
    const int lane = tid & 63;
    const int wid  = tid >> 6;

    float px[32], py[32], pz[32];
#pragma unroll
    for (int j = 0; j < 32; ++j) {
        const int i = tid + (j << 10);
        px[j] = p[3*i]; py[j] = p[3*i+1]; pz[j] = p[3*i+2];
    }

    for (int i = tid; i < N_PTS; i += 1024) pos[i] = -1;
    if (tid == 0) { fps[0] = 0; pos[0] = 0; s_last = 0; s_done = 0; s_cs = 0; }
    __syncthreads();

    int t = 1;
    while (t < M_PTS) {
        const int last = s_last;
        const float qx = p[3*last], qy = p[3*last+1], qz = p[3*last+2];
        float bd = -1.0f; int bi = 0;
#pragma unroll
        for (int j = 0; j < 32; ++j) {
            // match numpy: ((dx^2 + dy^2) + dz^2), no FMA contraction
            float dx = __fsub_rn(px[j], qx);
            float dy = __fsub_rn(py[j], qy);
            float dz = __fsub_rn(pz[j], qz);
            float d  = __fadd_rn(__fadd_rn(__fmul_rn(dx,dx), __fmul_rn(dy,dy)),
                                 __fmul_rn(dz,dz));
            const int i = tid + (j << 10);
            if (d > bd) { bd = d; bi = i; }   // ascending i scan keeps first on ties
        }
        // wave-level lex-max (d, then smaller idx)
#pragma unroll
        for (int off = 32; off > 0; off >>= 1) {
            float od = __shfl_xor(bd, off);
            int   oi = __shfl_xor(bi, off);
            if (od > bd || (od == bd && oi < bi)) { bd = od; bi = oi; }
        }
        if (lane == 0) { wv_d[wid] = bd; wv_i[wid] = bi; }
        __syncthreads();
        if (wid == 0) {
            float rd = (lane < 16) ? wv_d[lane] : -1.0f;
            int   ri = (lane < 16) ? wv_i[lane] : 0x7fffffff;
#pragma unroll
            for (int off = 8; off > 0; off >>= 1) {
                float od = __shfl_xor(rd, off);
                int   oi = __shfl_xor(ri, off);
                if (od > rd || (od == rd && oi < ri)) { rd = od; ri = oi; }
            }
            if (lane == 0) {
                int nxt = ri;
                if (pos[nxt] >= 0) { s_cs = pos[nxt]; s_done = 1; }
                else { pos[nxt] = t; fps[t] = nxt; s_last = nxt; }
            }
        }
        __syncthreads();
        if (s_done) break;
        ++t;
    }

    if (tid == 0) {
        if (s_done) { meta[0] = t; meta[1] = s_cs; meta[2] = t - s_cs; }
        else        { meta[0] = M_PTS; meta[1] = 0; meta[2] = 1; }
    }
    __syncthreads();
    if (s_done) {
        const int s = s_cs, L = t - s_cs;
        for (int u = t + tid; u < M_PTS; u += 1024)
            fps[u] = fps[s + (u - s) % L];
    }
    __syncthreads();
    for (int e = tid; e < M_PTS; e += 1024) {
        int id = fps[e];
        newp[3*e]   = p[3*id];
        newp[3*e+1] = p[3*id+1];
        newp[3*e+2] = p[3*id+2];
    }
}

// ---- kNN phase A: 8 slices/center; per-wave exact top-16 of its 256 points ----
// Threshold extraction over 4 packed u64s/thread: no blanking, no LDS, no barriers.
__global__ void __launch_bounds__(1024) knn_part_kernel(const float* __restrict__ p,
                                                        const int* __restrict__ fps,
                                                        const int* __restrict__ meta,
                                                        uint64* __restrict__ cand) {
    const int tid   = threadIdx.x;
    const int lane  = tid & 63;
    const int wid   = tid >> 6;           // 16 waves
    const int slice = blockIdx.x & 7;
    const int c0    = blockIdx.x >> 3;    // 16 center groups
    const int nun   = meta[0];

    for (int c = c0; c < nun && c < MAXC; c += 16) {
        const int cpt = fps[c];
        const float qx = p[3*cpt], qy = p[3*cpt+1], qz = p[3*cpt+2];
        const int base = slice << 12;     // slice*4096

        uint64 pk4[4];
#pragma unroll
        for (int j = 0; j < 4; ++j) {
            const int i = base + tid + (j << 10);
            float dx = p[3*i]   - qx;
            float dy = p[3*i+1] - qy;
            float dz = p[3*i+2] - qz;
            float d  = fmaf(dx, dx, fmaf(dy, dy, dz*dz));
            pk4[j] = ((uint64)dist_key(d) << 32) | (uint32)i;
        }

        uint64 lastv = 0ull;
        uint64* out = cand + ((size_t)c << 11) + (slice << 8) + (wid << 4);
        for (int r = 0; r < KNN; ++r) {
            uint64 m = ~0ull;
#pragma unroll
            for (int j = 0; j < 4; ++j) {
                const uint64 v = pk4[j];
                if (v > lastv && v < m) m = v;
            }
#pragma unroll
            for (int off = 32; off > 0; off >>= 1) {
                uint64 o = __shfl_xor(m, off);
                if (o < m) m = o;
            }
            if (lane == 0) out[r] = m;
            lastv = m;
        }
    }
}

// ---- kNN phase B: merge 2048 candidates/center (8 u64/thread, 256 threads) ----
__global__ void __launch_bounds__(256) knn_merge_kernel(const float* __restrict__ p,
                                                        const int* __restrict__ fps,
                                                        const int* __restrict__ meta,
                                                        const uint64* __restrict__ cand,
                                                        int* __restrict__ knn) {
    const int tid  = threadIdx.x;
    const int lane = tid & 63;
    const int wid  = tid >> 6;            // 4 waves
    const int nun  = meta[0];

    __shared__ uint64 wmin[4];
    __shared__ uint64 s_win;

    for (int c = blockIdx.x; c < nun; c += gridDim.x) {
        if (c < MAXC) {
            uint64 kc[8];
            const uint64* src = cand + ((size_t)c << 11);
#pragma unroll
            for (int j = 0; j < 8; ++j) kc[j] = src[tid + (j << 8)];

            uint64 lastv = 0ull;
            for (int r = 0; r < KNN; ++r) {
                uint64 m = ~0ull;
#pragma unroll
                for (int j = 0; j < 8; ++j) {
                    const uint64 v = kc[j];
                    if (v > lastv && v < m) m = v;
                }
#pragma unroll
                for (int off = 32; off > 0; off >>= 1) {
                    uint64 o = __shfl_xor(m, off);
                    if (o < m) m = o;
                }
                if (lane == 0) wmin[wid] = m;
                __syncthreads();
                if (tid == 0) {
                    uint64 w = wmin[0];
                    if (wmin[1] < w) w = wmin[1];
                    if (wmin[2] < w) w = wmin[2];
                    if (wmin[3] < w) w = wmin[3];
                    s_win = w;
                    knn[c*KNN + r] = (int)(w & 0xFFFFFFFFull);
                }
                __syncthreads();
                lastv = s_win;
            }
        } else {
            // correct-but-slow fallback (never expected): threshold extraction
            // over recomputed distances, full scan per round.
            const int cpt = fps[c];
            const float qx = p[3*cpt], qy = p[3*cpt+1], qz = p[3*cpt+2];
            uint64 lastv = 0ull;
            for (int r = 0; r < KNN; ++r) {
                uint64 m = ~0ull;
                for (int i = tid; i < N_PTS; i += 256) {
                    float dx = p[3*i]   - qx;
                    float dy = p[3*i+1] - qy;
                    float dz = p[3*i+2] - qz;
                    float d  = fmaf(dx, dx, fmaf(dy, dy, dz*dz));
                    uint64 v = ((uint64)dist_key(d) << 32) | (uint32)i;
                    if (v > lastv && v < m) m = v;
                }
#pragma unroll
                for (int off = 32; off > 0; off >>= 1) {
                    uint64 o = __shfl_xor(m, off);
                    if (o < m) m = o;
                }
                if (lane == 0) wmin[wid] = m;
                __syncthreads();
                if (tid == 0) {
                    uint64 w = wmin[0];
                    if (wmin[1] < w) w = wmin[1];
                    if (wmin[2] < w) w = wmin[2];
                    if (wmin[3] < w) w = wmin[3];
                    s_win = w;
                    knn[c*KNN + r] = (int)(w & 0xFFFFFFFFull);
                }
                __syncthreads();
                lastv = s_win;
            }
        }
    }
}

// ---- unique-slot stats: weighted per-channel sum/sumsq of h over nuniq slots ----
__global__ void __launch_bounds__(128) ustats_kernel(const float* __restrict__ p,
                                                     const float* __restrict__ x,
                                                     const float* __restrict__ W,
                                                     const int* __restrict__ knn,
                                                     const int* __restrict__ meta,
                                                     float* __restrict__ part) {
    __shared__ float g[GDIM];
    const int t = threadIdx.x;
    const int nun = meta[0], cs = meta[1], cl = meta[2];
    float s_sum = 0.f, s_sq = 0.f;
    for (int s = blockIdx.x; s < nun; s += SBLK) {
        float ls = 0.f, lq = 0.f;
        for (int k = 0; k < KNN; ++k) {
            const int pt = knn[s*KNN + k];
            if (t < 3)         g[t] = p[3*pt + t];
            else if (t < GDIM) g[t] = x[(pt << 6) + t - 3];
            __syncthreads();
            float acc = 0.f;
#pragma unroll
            for (int c = 0; c < GDIM; ++c) acc = fmaf(g[c], W[c*C_OUT + t], acc);
            ls += acc;
            lq = fmaf(acc, acc, lq);
            __syncthreads();
        }
        const float cf = (float)slot_count(s, nun, cs, cl, M_PTS);
        s_sum = fmaf(cf, ls, s_sum);
        s_sq  = fmaf(cf, lq, s_sq);
    }
    part[blockIdx.x*256 + t]       = s_sum;
    part[blockIdx.x*256 + 128 + t] = s_sq;
}

// ---------------- finalize BN: scale/shift per channel ----------------
__global__ void __launch_bounds__(128) bnfin_kernel(const float* __restrict__ part,
                                                    const float* __restrict__ gamma,
                                                    const float* __restrict__ beta,
                                                    float* __restrict__ scale,
                                                    float* __restrict__ shift) {
    const int t = threadIdx.x;
    float s = 0.f, q = 0.f;
    for (int b = 0; b < SBLK; ++b) {
        s += part[b*256 + t];
        q += part[b*256 + 128 + t];
    }
    const float inv = 1.0f / (float)(M_PTS * KNN);
    const float mean = s * inv;
    const float var  = q * inv - mean*mean;
    const float sc   = gamma[t] * rsqrtf(var + BN_EPS);
    scale[t] = sc;
    shift[t] = fmaf(-mean, sc, beta[t]);
}

// ---- unique-slot output rows: slot(m)==m for m<nuniq, write directly to xout ----
__global__ void __launch_bounds__(128) uout_kernel(const float* __restrict__ p,
                                                   const float* __restrict__ x,
                                                   const float* __restrict__ W,
                                                   const int* __restrict__ knn,
                                                   const int* __restrict__ meta,
                                                   const float* __restrict__ scale,
                                                   const float* __restrict__ shift,
                                                   float* __restrict__ xout) {
    __shared__ float g[GDIM];
    const int t = threadIdx.x;
    const int nun = meta[0];
    const float sc = scale[t], sh = shift[t];
    for (int s = blockIdx.x; s < nun; s += SBLK) {
        float mx = 0.f;   // max_k relu(y_k) == max(0, max_k y_k)
        for (int k = 0; k < KNN; ++k) {
            const int pt = knn[s*KNN + k];
            if (t < 3)         g[t] = p[3*pt + t];
            else if (t < GDIM) g[t] = x[(pt << 6) + t - 3];
            __syncthreads();
            float acc = 0.f;
#pragma unroll
            for (int c = 0; c < GDIM; ++c) acc = fmaf(g[c], W[c*C_OUT + t], acc);
            mx = fmaxf(mx, fmaf(acc, sc, sh));
            __syncthreads();
        }
        xout[s*C_OUT + t] = mx;
    }
}

// ---- broadcast periodic rows: xout[m] = xout[slot(m)] for m >= nuniq (float4) ----
__global__ void __launch_bounds__(256) bcast_kernel(const int* __restrict__ meta,
                                                    float* __restrict__ xout) {
    const int nun = meta[0], cs = meta[1], cl = meta[2];
    const int idx = blockIdx.x * 256 + threadIdx.x;      // float4 index
    const int m = nun + (idx >> 5);                      // 32 float4 per row
    if (m >= M_PTS) return;
    const int c4 = idx & 31;
    const int sl = cs + (m - cs) % cl;
    float4 v = ((const float4*)xout)[sl*32 + c4];
    ((float4*)xout)[(size_t)m*32 + c4] = v;
}

extern "C" void kernel_launch(void* const* d_in, const int* in_sizes, int n_in,
                              void* d_out, int out_size, void* d_ws, size_t ws_size,
                              hipStream_t stream) {
    (void)in_sizes; (void)n_in; (void)out_size; (void)ws_size;
    const float* p     = (const float*)d_in[0];
    const float* x     = (const float*)d_in[1];
    // d_in[2] = o (unused)
    const float* W     = (const float*)d_in[3];
    const float* gamma = (const float*)d_in[4];
    const float* beta  = (const float*)d_in[5];

    float* out  = (float*)d_out;
    float* newp = out;               // [M_PTS, 3]
    float* xout = out + M_PTS * 3;   // [M_PTS, C_OUT]

    char* ws = (char*)d_ws;
    int*    fps   = (int*)   (ws + OFF_FPS);
    int*    pos   = (int*)   (ws + OFF_POS);
    int*    meta  = (int*)   (ws + OFF_META);
    int*    knn   = (int*)   (ws + OFF_KNN);
    uint64* cand  = (uint64*)(ws + OFF_CAND);
    float*  part  = (float*) (ws + OFF_PART);
    float*  scale = (float*) (ws + OFF_SCALE);
    float*  shift = (float*) (ws + OFF_SHIFT);

    fps_kernel      <<<1, 1024, 0, stream>>>(p, fps, pos, meta, newp);
    knn_part_kernel <<<128, 1024, 0, stream>>>(p, fps, meta, cand);
    knn_merge_kernel<<<64, 256, 0, stream>>>(p, fps, meta, cand, knn);
    ustats_kernel   <<<SBLK, 128, 0, stream>>>(p, x, W, knn, meta, part);
    bnfin_kernel    <<<1, 128, 0, stream>>>(part, gamma, beta, scale, shift);
    uout_kernel     <<<SBLK, 128, 0, stream>>>(p, x, W, knn, meta, scale, shift, xout);
    bcast_kernel    <<<M_PTS*32/256, 256, 0, stream>>>(meta, xout);
}

// Round 7
// 80.043 us; speedup vs baseline: 1.4983x; 1.4983x over previous
//
#include <hip/hip_runtime.h>

#define N_PTS 32768
#define M_PTS 8192      // N / STRIDE
#define C_IN  64
#define C_OUT 128
#define KNN   16
#define GDIM  67        // 3 + C_IN
#define BN_EPS 1e-5f
#define SBLK  64        // blocks for ustats/uout grid-stride
#define MAXC  64        // centers with candidate-buffer fast path

// workspace offsets (bytes)
#define OFF_FPS   0u          // int[M_PTS] (only first nuniq used)
#define OFF_META  163840u     // int[8]: [0]=nuniq [1]=cycStart [2]=cycLen
#define OFF_KNN   163904u     // int[M_PTS*KNN]
#define OFF_CAND  688192u     // u64[MAXC*2048]
#define OFF_PART  1736768u    // float[SBLK*256]
#define OFF_SCALE 1802304u    // float[C_OUT]
#define OFF_SHIFT 1802816u    // float[C_OUT]

typedef unsigned int uint32;
typedef unsigned long long uint64;

// multiplicity of unique slot s in the length-M periodic index sequence
__device__ __forceinline__ int slot_count(int s, int nun, int cs, int cl, int M) {
    if (s < cs) return 1;                 // pre-cycle slot: occurs once
    const int E = M - nun;                // extended (periodic) occurrences
    const int base = E / cl, rem = E % cl;
    const int start = (nun - cs) % cl;    // residue of first extended index
    int off = (s - cs) - start; if (off < 0) off += cl;
    return 1 + base + (off < rem ? 1 : 0);
}

__device__ __forceinline__ uint32 dist_key(float d) {
    uint32 u = __float_as_uint(d);
    return (u & 0x80000000u) ? ~u : (u | 0x80000000u);
}

// ---------------- FPS chain only: serial argmax steps, LDS chain, no pos[] ------
__global__ void __launch_bounds__(1024) fps_chain_kernel(const float* __restrict__ p,
                                                         int* __restrict__ fps,
                                                         int* __restrict__ meta) {
    __shared__ int   s_chain[M_PTS];     // 32 KB
    __shared__ float wv_d[16];
    __shared__ int   wv_i[16];
    __shared__ int s_last, s_done, s_cs, s_win, s_found;
    const int tid  = threadIdx.x;
    const int lane = tid & 63;
    const int wid  = tid >> 6;

    if (tid == 0) { s_chain[0] = 0; s_last = 0; s_done = 0; s_cs = 0; }
    __syncthreads();

    int t = 1;
    while (t < M_PTS) {
        const int last = s_last;
        const float qx = p[3*last], qy = p[3*last+1], qz = p[3*last+2];
        float bd = -1.0f; int bi = 0;
#pragma unroll
        for (int j = 0; j < 32; ++j) {
            const int i = tid + (j << 10);
            // match numpy: ((dx^2 + dy^2) + dz^2), no FMA contraction
            float dx = __fsub_rn(p[3*i],   qx);
            float dy = __fsub_rn(p[3*i+1], qy);
            float dz = __fsub_rn(p[3*i+2], qz);
            float d  = __fadd_rn(__fadd_rn(__fmul_rn(dx,dx), __fmul_rn(dy,dy)),
                                 __fmul_rn(dz,dz));
            if (d > bd) { bd = d; bi = i; }   // ascending i keeps first on ties
        }
        // wave-level lex-max (d, then smaller idx)
#pragma unroll
        for (int off = 32; off > 0; off >>= 1) {
            float od = __shfl_xor(bd, off);
            int   oi = __shfl_xor(bi, off);
            if (od > bd || (od == bd && oi < bi)) { bd = od; bi = oi; }
        }
        if (lane == 0) { wv_d[wid] = bd; wv_i[wid] = bi; }
        __syncthreads();
        if (wid == 0) {
            float rd = (lane < 16) ? wv_d[lane] : -1.0f;
            int   ri = (lane < 16) ? wv_i[lane] : 0x7fffffff;
#pragma unroll
            for (int off = 8; off > 0; off >>= 1) {
                float od = __shfl_xor(rd, off);
                int   oi = __shfl_xor(ri, off);
                if (od > rd || (od == rd && oi < ri)) { rd = od; ri = oi; }
            }
            if (lane == 0) { s_win = ri; s_found = -1; }
        }
        __syncthreads();
        const int nxt = s_win;
        // block-parallel cycle search over the chain (entries are unique)
        for (int i = tid; i < t; i += 1024)
            if (s_chain[i] == nxt) s_found = i;
        __syncthreads();
        if (tid == 0) {
            if (s_found >= 0) { s_cs = s_found; s_done = 1; }
            else { s_chain[t] = nxt; s_last = nxt; }
        }
        __syncthreads();
        if (s_done) break;
        ++t;
    }

    if (tid == 0) {
        if (s_done) { meta[0] = t; meta[1] = s_cs; meta[2] = t - s_cs; }
        else        { meta[0] = M_PTS; meta[1] = 0; meta[2] = 1; }
    }
    const int nun = s_done ? t : M_PTS;
    for (int i = tid; i < nun; i += 1024) fps[i] = s_chain[i];
}

// ---- kNN phase A (+ parallel newp fill): 8 slices/center, per-wave top-16 ------
__global__ void __launch_bounds__(1024) knn_part_kernel(const float* __restrict__ p,
                                                        const int* __restrict__ fps,
                                                        const int* __restrict__ meta,
                                                        uint64* __restrict__ cand,
                                                        float* __restrict__ newp) {
    const int tid   = threadIdx.x;
    const int lane  = tid & 63;
    const int wid   = tid >> 6;           // 16 waves
    const int slice = blockIdx.x & 7;
    const int c0    = blockIdx.x >> 3;    // 16 center groups
    const int nun   = meta[0];
    const int cs    = meta[1], cl = meta[2];

    // parallel newp fill: 131k threads cover 8192 rows in one pass
    for (int e = blockIdx.x * 1024 + tid; e < M_PTS; e += gridDim.x * 1024) {
        const int sl = (e < nun) ? e : cs + (e - cs) % cl;
        const int id = fps[sl];
        newp[3*e]   = p[3*id];
        newp[3*e+1] = p[3*id+1];
        newp[3*e+2] = p[3*id+2];
    }

    for (int c = c0; c < nun && c < MAXC; c += 16) {
        const int cpt = fps[c];
        const float qx = p[3*cpt], qy = p[3*cpt+1], qz = p[3*cpt+2];
        const int base = slice << 12;     // slice*4096

        uint64 pk4[4];
#pragma unroll
        for (int j = 0; j < 4; ++j) {
            const int i = base + tid + (j << 10);
            float dx = p[3*i]   - qx;
            float dy = p[3*i+1] - qy;
            float dz = p[3*i+2] - qz;
            float d  = fmaf(dx, dx, fmaf(dy, dy, dz*dz));
            pk4[j] = ((uint64)dist_key(d) << 32) | (uint32)i;
        }

        uint64 lastv = 0ull;
        uint64* out = cand + ((size_t)c << 11) + (slice << 8) + (wid << 4);
        for (int r = 0; r < KNN; ++r) {
            uint64 m = ~0ull;
#pragma unroll
            for (int j = 0; j < 4; ++j) {
                const uint64 v = pk4[j];
                if (v > lastv && v < m) m = v;
            }
#pragma unroll
            for (int off = 32; off > 0; off >>= 1) {
                uint64 o = __shfl_xor(m, off);
                if (o < m) m = o;
            }
            if (lane == 0) out[r] = m;
            lastv = m;
        }
    }
}

// ---- kNN phase B: merge 2048 candidates/center (8 u64/thread, 256 threads) ----
__global__ void __launch_bounds__(256) knn_merge_kernel(const float* __restrict__ p,
                                                        const int* __restrict__ fps,
                                                        const int* __restrict__ meta,
                                                        const uint64* __restrict__ cand,
                                                        int* __restrict__ knn) {
    const int tid  = threadIdx.x;
    const int lane = tid & 63;
    const int wid  = tid >> 6;            // 4 waves
    const int nun  = meta[0];

    __shared__ uint64 wmin[4];
    __shared__ uint64 s_win;

    for (int c = blockIdx.x; c < nun; c += gridDim.x) {
        if (c < MAXC) {
            uint64 kc[8];
            const uint64* src = cand + ((size_t)c << 11);
#pragma unroll
            for (int j = 0; j < 8; ++j) kc[j] = src[tid + (j << 8)];

            uint64 lastv = 0ull;
            for (int r = 0; r < KNN; ++r) {
                uint64 m = ~0ull;
#pragma unroll
                for (int j = 0; j < 8; ++j) {
                    const uint64 v = kc[j];
                    if (v > lastv && v < m) m = v;
                }
#pragma unroll
                for (int off = 32; off > 0; off >>= 1) {
                    uint64 o = __shfl_xor(m, off);
                    if (o < m) m = o;
                }
                if (lane == 0) wmin[wid] = m;
                __syncthreads();
                if (tid == 0) {
                    uint64 w = wmin[0];
                    if (wmin[1] < w) w = wmin[1];
                    if (wmin[2] < w) w = wmin[2];
                    if (wmin[3] < w) w = wmin[3];
                    s_win = w;
                    knn[c*KNN + r] = (int)(w & 0xFFFFFFFFull);
                }
                __syncthreads();
                lastv = s_win;
            }
        } else {
            // correct-but-slow fallback (never expected with nuniq small)
            const int cpt = fps[c];
            const float qx = p[3*cpt], qy = p[3*cpt+1], qz = p[3*cpt+2];
            uint64 lastv = 0ull;
            for (int r = 0; r < KNN; ++r) {
                uint64 m = ~0ull;
                for (int i = tid; i < N_PTS; i += 256) {
                    float dx = p[3*i]   - qx;
                    float dy = p[3*i+1] - qy;
                    float dz = p[3*i+2] - qz;
                    float d  = fmaf(dx, dx, fmaf(dy, dy, dz*dz));
                    uint64 v = ((uint64)dist_key(d) << 32) | (uint32)i;
                    if (v > lastv && v < m) m = v;
                }
#pragma unroll
                for (int off = 32; off > 0; off >>= 1) {
                    uint64 o = __shfl_xor(m, off);
                    if (o < m) m = o;
                }
                if (lane == 0) wmin[wid] = m;
                __syncthreads();
                if (tid == 0) {
                    uint64 w = wmin[0];
                    if (wmin[1] < w) w = wmin[1];
                    if (wmin[2] < w) w = wmin[2];
                    if (wmin[3] < w) w = wmin[3];
                    s_win = w;
                    knn[c*KNN + r] = (int)(w & 0xFFFFFFFFull);
                }
                __syncthreads();
                lastv = s_win;
            }
        }
    }
}

// ---- unique-slot stats: weighted per-channel sum/sumsq of h over nuniq slots ----
__global__ void __launch_bounds__(128) ustats_kernel(const float* __restrict__ p,
                                                     const float* __restrict__ x,
                                                     const float* __restrict__ W,
                                                     const int* __restrict__ knn,
                                                     const int* __restrict__ meta,
                                                     float* __restrict__ part) {
    __shared__ float g[GDIM];
    const int t = threadIdx.x;
    const int nun = meta[0], cs = meta[1], cl = meta[2];
    float s_sum = 0.f, s_sq = 0.f;
    for (int s = blockIdx.x; s < nun; s += SBLK) {
        float ls = 0.f, lq = 0.f;
        for (int k = 0; k < KNN; ++k) {
            const int pt = knn[s*KNN + k];
            if (t < 3)         g[t] = p[3*pt + t];
            else if (t < GDIM) g[t] = x[(pt << 6) + t - 3];
            __syncthreads();
            float acc = 0.f;
#pragma unroll
            for (int c = 0; c < GDIM; ++c) acc = fmaf(g[c], W[c*C_OUT + t], acc);
            ls += acc;
            lq = fmaf(acc, acc, lq);
            __syncthreads();
        }
        const float cf = (float)slot_count(s, nun, cs, cl, M_PTS);
        s_sum = fmaf(cf, ls, s_sum);
        s_sq  = fmaf(cf, lq, s_sq);
    }
    part[blockIdx.x*256 + t]       = s_sum;
    part[blockIdx.x*256 + 128 + t] = s_sq;
}

// ---------------- finalize BN: scale/shift per channel ----------------
__global__ void __launch_bounds__(128) bnfin_kernel(const float* __restrict__ part,
                                                    const float* __restrict__ gamma,
                                                    const float* __restrict__ beta,
                                                    float* __restrict__ scale,
                                                    float* __restrict__ shift) {
    const int t = threadIdx.x;
    float s = 0.f, q = 0.f;
    for (int b = 0; b < SBLK; ++b) {
        s += part[b*256 + t];
        q += part[b*256 + 128 + t];
    }
    const float inv = 1.0f / (float)(M_PTS * KNN);
    const float mean = s * inv;
    const float var  = q * inv - mean*mean;
    const float sc   = gamma[t] * rsqrtf(var + BN_EPS);
    scale[t] = sc;
    shift[t] = fmaf(-mean, sc, beta[t]);
}

// ---- unique-slot output rows: slot(m)==m for m<nuniq, write directly to xout ----
__global__ void __launch_bounds__(128) uout_kernel(const float* __restrict__ p,
                                                   const float* __restrict__ x,
                                                   const float* __restrict__ W,
                                                   const int* __restrict__ knn,
                                                   const int* __restrict__ meta,
                                                   const float* __restrict__ scale,
                                                   const float* __restrict__ shift,
                                                   float* __restrict__ xout) {
    __shared__ float g[GDIM];
    const int t = threadIdx.x;
    const int nun = meta[0];
    const float sc = scale[t], sh = shift[t];
    for (int s = blockIdx.x; s < nun; s += SBLK) {
        float mx = 0.f;   // max_k relu(y_k) == max(0, max_k y_k)
        for (int k = 0; k < KNN; ++k) {
            const int pt = knn[s*KNN + k];
            if (t < 3)         g[t] = p[3*pt + t];
            else if (t < GDIM) g[t] = x[(pt << 6) + t - 3];
            __syncthreads();
            float acc = 0.f;
#pragma unroll
            for (int c = 0; c < GDIM; ++c) acc = fmaf(g[c], W[c*C_OUT + t], acc);
            mx = fmaxf(mx, fmaf(acc, sc, sh));
            __syncthreads();
        }
        xout[s*C_OUT + t] = mx;
    }
}

// ---- broadcast periodic rows: xout[m] = xout[slot(m)] for m >= nuniq (float4) ----
__global__ void __launch_bounds__(256) bcast_kernel(const int* __restrict__ meta,
                                                    float* __restrict__ xout) {
    const int nun = meta[0], cs = meta[1], cl = meta[2];
    const int idx = blockIdx.x * 256 + threadIdx.x;      // float4 index
    const int m = nun + (idx >> 5);                      // 32 float4 per row
    if (m >= M_PTS) return;
    const int c4 = idx & 31;
    const int sl = cs + (m - cs) % cl;
    float4 v = ((const float4*)xout)[sl*32 + c4];
    ((float4*)xout)[(size_t)m*32 + c4] = v;
}

extern "C" void kernel_launch(void* const* d_in, const int* in_sizes, int n_in,
                              void* d_out, int out_size, void* d_ws, size_t ws_size,
                              hipStream_t stream) {
    (void)in_sizes; (void)n_in; (void)out_size; (void)ws_size;
    const float* p     = (const float*)d_in[0];
    const float* x     = (const float*)d_in[1];
    // d_in[2] = o (unused)
    const float* W     = (const float*)d_in[3];
    const float* gamma = (const float*)d_in[4];
    const float* beta  = (const float*)d_in[5];

    float* out  = (float*)d_out;
    float* newp = out;               // [M_PTS, 3]
    float* xout = out + M_PTS * 3;   // [M_PTS, C_OUT]

    char* ws = (char*)d_ws;
    int*    fps   = (int*)   (ws + OFF_FPS);
    int*    meta  = (int*)   (ws + OFF_META);
    int*    knn   = (int*)   (ws + OFF_KNN);
    uint64* cand  = (uint64*)(ws + OFF_CAND);
    float*  part  = (float*) (ws + OFF_PART);
    float*  scale = (float*) (ws + OFF_SCALE);
    float*  shift = (float*) (ws + OFF_SHIFT);

    fps_chain_kernel<<<1, 1024, 0, stream>>>(p, fps, meta);
    knn_part_kernel <<<128, 1024, 0, stream>>>(p, fps, meta, cand, newp);
    knn_merge_kernel<<<64, 256, 0, stream>>>(p, fps, meta, cand, knn);
    ustats_kernel   <<<SBLK, 128, 0, stream>>>(p, x, W, knn, meta, part);
    bnfin_kernel    <<<1, 128, 0, stream>>>(part, gamma, beta, scale, shift);
    uout_kernel     <<<SBLK, 128, 0, stream>>>(p, x, W, knn, meta, scale, shift, xout);
    bcast_kernel    <<<M_PTS*32/256, 256, 0, stream>>>(meta, xout);
}